// Round 3
// baseline (548.211 us; speedup 1.0000x reference)
//
#include <hip/hip_runtime.h>
#include <math.h>

#define EMB 1024
#define HID 1024
#define VOCAB 50257
#define NBLK 512                                  // 2 blocks/CU -> co-residency guaranteed
#define RPB 99                                    // logits rows per block (512*99 >= 50257)
#define NBLK_LG ((VOCAB + RPB - 1) / RPB)         // 508 blocks actually own rows
#define HOUT_OFF VOCAB
#define COUT_OFF (VOCAB + 2*HID)

// ws float offsets: [0..3] = 3 barrier counters (uint), then h1, h2, partials
#define H1_OFF 16
#define H2_OFF (16 + HID)
#define MP_OFF (16 + 2*HID)
#define SP_OFF (MP_OFF + NBLK)

__device__ __forceinline__ float wave_reduce(float v) {
#pragma unroll
    for (int o = 32; o > 0; o >>= 1) v += __shfl_down(v, o);
    return v;
}

__device__ __forceinline__ float sigmoidf_(float x) { return 1.0f / (1.0f + expf(-x)); }

__global__ void init_bar(unsigned* __restrict__ bar) {
    if (threadIdx.x < 3) bar[threadIdx.x] = 0u;
}

// Device-scope grid barrier: one counter per barrier, used once per launch,
// zeroed by init_bar. Safe: all NBLK blocks are co-resident (2 blocks/CU).
__device__ __forceinline__ void grid_barrier(unsigned* ctr) {
    __syncthreads();
    if (threadIdx.x == 0) {
        __threadfence();   // publish this block's global writes (device scope)
        __hip_atomic_fetch_add(ctr, 1u, __ATOMIC_ACQ_REL, __HIP_MEMORY_SCOPE_AGENT);
        while (__hip_atomic_load(ctr, __ATOMIC_ACQUIRE, __HIP_MEMORY_SCOPE_AGENT) < NBLK)
            __builtin_amdgcn_s_sleep(1);
    }
    __syncthreads();
}

// One LSTM unit: waves 0..3 compute gates i,f,g,o (8 KB of weight rows),
// thread 0 does the cell math and writes h,c.
__device__ __forceinline__ void lstm_unit_step(
    int unit, int wave, int lane,
    const float4* __restrict__ xp, bool do_relu,
    const float* __restrict__ Wih, const float* __restrict__ Whh,
    const float* __restrict__ bih, const float* __restrict__ bhh,
    const float4* __restrict__ hp, const float* __restrict__ c_prev,
    float* __restrict__ h_dst, float* __restrict__ out_h, float* __restrict__ out_c,
    float* gates)
{
    const int row = wave * HID + unit;
    const float4* wih = (const float4*)(Wih + (size_t)row * EMB);
    const float4* whh = (const float4*)(Whh + (size_t)row * HID);
    float acc = 0.f;
#pragma unroll
    for (int j = 0; j < 4; ++j) {
        float4 xv = xp[j*64 + lane];
        if (do_relu) {
            xv.x = fmaxf(xv.x, 0.f); xv.y = fmaxf(xv.y, 0.f);
            xv.z = fmaxf(xv.z, 0.f); xv.w = fmaxf(xv.w, 0.f);
        }
        float4 a = wih[j*64 + lane];
        acc += a.x*xv.x + a.y*xv.y + a.z*xv.z + a.w*xv.w;
        float4 hv = hp[j*64 + lane];
        float4 bw = whh[j*64 + lane];
        acc += bw.x*hv.x + bw.y*hv.y + bw.z*hv.z + bw.w*hv.w;
    }
    acc = wave_reduce(acc);
    if (lane == 0) gates[wave] = acc + bih[row] + bhh[row];
    __syncthreads();
    if (wave == 0 && lane == 0) {
        float ig = sigmoidf_(gates[0]);
        float fg = sigmoidf_(gates[1]);
        float gg = tanhf(gates[2]);
        float og = sigmoidf_(gates[3]);
        float c  = fg * c_prev[unit] + ig * gg;
        float h  = og * tanhf(c);
        h_dst[unit] = h;
        out_h[unit] = h;
        out_c[unit] = c;
    }
    __syncthreads();
}

__global__ __launch_bounds__(256) void fused_decoder(
    const float* __restrict__ emb, const int* __restrict__ word,
    const float* __restrict__ Wih0, const float* __restrict__ Whh0,
    const float* __restrict__ bih0, const float* __restrict__ bhh0,
    const float* __restrict__ Wih1, const float* __restrict__ Whh1,
    const float* __restrict__ bih1, const float* __restrict__ bhh1,
    const float* __restrict__ Wout, const float* __restrict__ bout,
    const float* __restrict__ h0, const float* __restrict__ c0,
    float* __restrict__ out, float* __restrict__ ws)
{
    const int b = blockIdx.x, tid = threadIdx.x;
    const int wave = tid >> 6, lane = tid & 63;
    unsigned* bar = (unsigned*)ws;
    float* h1 = ws + H1_OFF;
    float* h2 = ws + H2_OFF;
    float* mp = ws + MP_OFF;
    float* sp = ws + SP_OFF;

    __shared__ float gates[4];
    __shared__ float ms16[16], ss16[16];
    __shared__ float red_m[256], red_s[256];

    // ---- Phase A: LSTM layer 0, units 2b and 2b+1 ----
    {
        const float4* xp = (const float4*)(emb + (size_t)word[0] * EMB);
        const float4* hp = (const float4*)h0;
        lstm_unit_step(2*b+0, wave, lane, xp, true, Wih0, Whh0, bih0, bhh0,
                       hp, c0, h1, out + HOUT_OFF, out + COUT_OFF, gates);
        lstm_unit_step(2*b+1, wave, lane, xp, true, Wih0, Whh0, bih0, bhh0,
                       hp, c0, h1, out + HOUT_OFF, out + COUT_OFF, gates);
    }
    grid_barrier(&bar[0]);

    // ---- Phase B: LSTM layer 1, x = h1 ----
    {
        const float4* xp = (const float4*)h1;
        const float4* hp = (const float4*)(h0 + HID);
        lstm_unit_step(2*b+0, wave, lane, xp, false, Wih1, Whh1, bih1, bhh1,
                       hp, c0 + HID, h2, out + HOUT_OFF + HID, out + COUT_OFF + HID, gates);
        lstm_unit_step(2*b+1, wave, lane, xp, false, Wih1, Whh1, bih1, bhh1,
                       hp, c0 + HID, h2, out + HOUT_OFF + HID, out + COUT_OFF + HID, gates);
    }
    grid_barrier(&bar[1]);

    // ---- Phase C: logits rows [b*RPB, min(b*RPB+RPB, VOCAB)) ----
    // 16 lanes per row, 16 rows per iteration, 7 iterations.
    {
        const int l = tid & 15, g = tid >> 4;
        const int base = b * RPB;
        const int rend = (base + RPB < VOCAB) ? base + RPB : VOCAB;
        float M = -INFINITY, S = 0.f;
        const float4* xp = (const float4*)h2;
        if (b < NBLK_LG) {
            for (int it = 0; it < 7; ++it) {
                const int row = base + it*16 + g;
                if (row < rend) {
                    const float4* wr = (const float4*)(Wout + (size_t)row * HID);
                    float a0 = 0.f, a1 = 0.f, a2 = 0.f, a3 = 0.f;
#pragma unroll
                    for (int j = 0; j < 4; ++j) {
                        float4 w0 = wr[l+16*(4*j+0)], x0 = xp[l+16*(4*j+0)];
                        float4 w1 = wr[l+16*(4*j+1)], x1 = xp[l+16*(4*j+1)];
                        float4 w2 = wr[l+16*(4*j+2)], x2 = xp[l+16*(4*j+2)];
                        float4 w3 = wr[l+16*(4*j+3)], x3 = xp[l+16*(4*j+3)];
                        a0 += w0.x*x0.x + w0.y*x0.y + w0.z*x0.z + w0.w*x0.w;
                        a1 += w1.x*x1.x + w1.y*x1.y + w1.z*x1.z + w1.w*x1.w;
                        a2 += w2.x*x2.x + w2.y*x2.y + w2.z*x2.z + w2.w*x2.w;
                        a3 += w3.x*x3.x + w3.y*x3.y + w3.z*x3.z + w3.w*x3.w;
                    }
                    float acc = (a0 + a1) + (a2 + a3);
                    acc += __shfl_xor(acc, 8);
                    acc += __shfl_xor(acc, 4);
                    acc += __shfl_xor(acc, 2);
                    acc += __shfl_xor(acc, 1);
                    if (l == 0) {
                        float logit = acc + bout[row];
                        out[row] = logit;
                        float nm = fmaxf(M, logit);
                        S = S * expf(M - nm) + expf(logit - nm);
                        M = nm;
                    }
                }
            }
        }
        if (l == 0) { ms16[g] = M; ss16[g] = S; }
        __syncthreads();
        if (tid == 0 && b < NBLK_LG) {
            float Mb = -INFINITY, Sb = 0.f;
#pragma unroll
            for (int i2 = 0; i2 < 16; ++i2) {
                float m = ms16[i2];
                if (m > -INFINITY) {
                    float nm = fmaxf(Mb, m);
                    Sb = Sb * expf(Mb - nm) + ss16[i2] * expf(m - nm);
                    Mb = nm;
                }
            }
            mp[b] = Mb; sp[b] = Sb;
        }
    }
    grid_barrier(&bar[2]);

    // ---- Phase D: every block folds all partials -> Z, then subtracts Z
    // over the rows it wrote itself in phase C (same XCD, L2-hot). ----
    {
        float M = -INFINITY, S = 0.f;
        for (int p = tid; p < NBLK_LG; p += 256) {
            float m = mp[p];
            if (m > -INFINITY) {
                float s = sp[p];
                float nm = fmaxf(M, m);
                S = S * expf(M - nm) + s * expf(m - nm);
                M = nm;
            }
        }
        red_m[tid] = M; red_s[tid] = S;
        __syncthreads();
        for (int o = 128; o > 0; o >>= 1) {
            if (tid < o) {
                float m1 = red_m[tid], s1 = red_s[tid];
                float m2 = red_m[tid+o], s2 = red_s[tid+o];
                float nm = fmaxf(m1, m2);
                red_s[tid] = s1 * expf(m1 - nm) + s2 * expf(m2 - nm);
                red_m[tid] = nm;
            }
            __syncthreads();
        }
        const float Z = red_m[0] + logf(red_s[0]);
        const int base = b * RPB;
        const int rend = (base + RPB < VOCAB) ? base + RPB : VOCAB;
        for (int i = base + tid; i < rend; i += 256) out[i] -= Z;
    }
}

extern "C" void kernel_launch(void* const* d_in, const int* in_sizes, int n_in,
                              void* d_out, int out_size, void* d_ws, size_t ws_size,
                              hipStream_t stream)
{
    const int*   word = (const int*)  d_in[0];
    const float* h0   = (const float*)d_in[1];
    const float* c0   = (const float*)d_in[2];
    const float* emb  = (const float*)d_in[3];
    const float* Wih0 = (const float*)d_in[4];
    const float* Whh0 = (const float*)d_in[5];
    const float* bih0 = (const float*)d_in[6];
    const float* bhh0 = (const float*)d_in[7];
    const float* Wih1 = (const float*)d_in[8];
    const float* Whh1 = (const float*)d_in[9];
    const float* bih1 = (const float*)d_in[10];
    const float* bhh1 = (const float*)d_in[11];
    const float* Wout = (const float*)d_in[12];
    const float* bout = (const float*)d_in[13];

    float* out = (float*)d_out;
    float* ws  = (float*)d_ws;

    init_bar<<<1, 64, 0, stream>>>((unsigned*)ws);
    fused_decoder<<<NBLK, 256, 0, stream>>>(emb, word, Wih0, Whh0, bih0, bhh0,
                                            Wih1, Whh1, bih1, bhh1, Wout, bout,
                                            h0, c0, out, ws);
}